// Round 4
// baseline (135.021 us; speedup 1.0000x reference)
//
#include <hip/hip_runtime.h>
#include <hip/hip_bf16.h>
#include <hip/hip_fp16.h>

// Problem constants
#define NT 8192            // tokens
#define NQB 6              // qubits
#define NL 2               // layers
// Attention kernel tiling
#define JSPLIT 16
#define JSLICE (NT / JSPLIT)     // 512 keys per block
#define CHUNK 32                 // keys staged per LDS chunk (one W-MFMA K-group)
#define NCHUNK (JSLICE / CHUNK)  // 16
#define IPW 32                   // query rows per wave (2 rowtiles of 16)
#define WPB 4                    // waves per block
#define IPB (IPW * WPB)          // 128 rows per block
#define NBI (NT / IPB)           // 64 i-blocks
#define WSTRIDE 40               // fp16 units per W-transpose row (80B: 16B-aligned, bank-spread)

typedef _Float16 f16x8 __attribute__((ext_vector_type(8)));
typedef float f32x4 __attribute__((ext_vector_type(4)));

static __device__ __forceinline__ unsigned int pack_h2(float a, float b) {
  unsigned short lo = __builtin_bit_cast(unsigned short, (_Float16)a);
  unsigned short hi = __builtin_bit_cast(unsigned short, (_Float16)b);
  return (unsigned int)lo | ((unsigned int)hi << 16);
}

static __device__ __forceinline__ unsigned int pkrtz(float a, float b) {
  return __builtin_bit_cast(unsigned int, __builtin_amdgcn_cvt_pkrtz(a, b));
}

// one CNOT's index map: src(p) = p ^ (bit_c(p) ? mask_t : 0)  (an involution)
static __device__ __forceinline__ int cnot_src(int p, int q) {
  const int mc = 1 << (5 - q);
  const int mt = 1 << (5 - ((q + 1) % NQB));
  return (p & mc) ? (p ^ mt) : p;
}

// direct-to-LDS 16B async copy (gfx950). LDS dest is wave-uniform base + lane*16.
#define GLOAD_LDS16(g, l)                                      \
  __builtin_amdgcn_global_load_lds(                            \
      (const __attribute__((address_space(1))) void*)(g),      \
      (__attribute__((address_space(3))) void*)(l), 16, 0, 0)

// ---------------------------------------------------------------------------
// Kernel 1: statevector prep with FUSED transcendental precompute.
// One wave per (token, set); lane = basis state. Per-lane sincos budget: 1
// shared table sincos (lanes 0-5: x/2; 8-13: RY l0; 16-21: RY l1, shfl
// broadcast) + 2 per-lane RZ-phase sincos. Outputs (fp16):
//  set0: Are linear  [tok][u32 e]
//  set1: Bk  uint4-XOR-preswizzled (u stored at u^(tok&15)) for conflict-free
//        swizzled ds_read after LINEAR global_load_lds staging in attn
//  set2: Vt [16][NT] fp16: rows 0..5 = <Z_q> hi, 6 = 1.0 (den), 7 = 0,
//        rows 8..13 = <Z_q> residual (lo), 14..15 = 0
// ---------------------------------------------------------------------------
__global__ __launch_bounds__(256) void prep_kernel(
    const float* __restrict__ x, const float* __restrict__ pq,
    const float* __restrict__ pk, const float* __restrict__ pv,
    unsigned int* __restrict__ Are, unsigned int* __restrict__ Bk,
    unsigned short* __restrict__ Vt)
{
  const int wid  = blockIdx.x * 4 + (threadIdx.x >> 6);
  const int lane = threadIdx.x & 63;
  const int set  = wid >> 13;          // / 8192
  const int tok  = wid & (NT - 1);
  const float* pp = (set == 0) ? pq : ((set == 1) ? pk : pv);

  // sigma(l): product-state evaluation index; inv = sigma^{-1}(l)
  int m = lane;
#pragma unroll
  for (int q = 5; q >= 0; --q) m = cnot_src(m, q);
  int inv = lane;
#pragma unroll
  for (int q = 0; q < 6; ++q) inv = cnot_src(inv, q);

  // one shared sincos: lanes 0-5 -> x/2; 8-13 -> RY layer0 /2; 16-21 -> RY layer1 /2
  float a = 0.f;
  if (lane < 6)                    a = 0.5f * x[tok * NQB + lane];
  else if (lane >= 8 && lane < 14) a = 0.5f * pp[(lane - 8) * 2];
  else if (lane >= 16 && lane < 22) a = 0.5f * pp[12 + (lane - 16) * 2];
  float sa, ca;
  __sincosf(a, &sa, &ca);

  // layer-0 RY magnitudes via angle addition: sincos(x/2 + p/2)
  float R = 1.f;
#pragma unroll
  for (int q = 0; q < 6; ++q) {
    const float tqs = __shfl(sa, q, 64),     tqc = __shfl(ca, q, 64);
    const float prs = __shfl(sa, 8 + q, 64), prc = __shfl(ca, 8 + q, 64);
    const float s = tqs * prc + tqc * prs;
    const float c = tqc * prc - tqs * prs;
    R *= ((m >> (5 - q)) & 1) ? s : c;
  }
  // layer-0 RZ phase at index m (per-lane)
  float phi0 = 0.f;
#pragma unroll
  for (int q = 0; q < 6; ++q) {
    const float bh = 0.5f * pp[q * 2 + 1];
    phi0 += ((m >> (5 - q)) & 1) ? bh : -bh;
  }
  float s0, c0;
  __sincosf(phi0, &s0, &c0);
  float re = R * c0, im = R * s0;

  // layer-1 RYs (entangled now -> shuffles); (s,c) from lanes 16-21
#pragma unroll
  for (int q = 0; q < 6; ++q) {
    const int mask = 1 << (5 - q);
    const float rcs = __shfl(sa, 16 + q, 64), rcc = __shfl(ca, 16 + q, 64);
    const float pre = __shfl_xor(re, mask, 64);
    const float pim = __shfl_xor(im, mask, 64);
    const float se = (lane & mask) ? rcs : -rcs;
    re = fmaf(se, pre, rcc * re);
    im = fmaf(se, pim, rcc * im);
  }
  // layer-1 RZ phase at index lane (per-lane)
  float phi1 = 0.f;
#pragma unroll
  for (int q = 0; q < 6; ++q) {
    const float bh = 0.5f * pp[12 + q * 2 + 1];
    phi1 += ((lane >> (5 - q)) & 1) ? bh : -bh;
  }
  float s1, c1;
  __sincosf(phi1, &s1, &c1);
  const float fre = re * c1 - im * s1;
  const float fim = re * s1 + im * c1;

  if (set == 0) {
    Are[tok * 64 + inv] = pack_h2(fre, fim);     // [qr, qi] fp16, linear
  } else if (set == 1) {
    const int sidx = ((((inv >> 2) ^ (tok & 15)) << 2) | (inv & 3));
    Bk[tok * 64 + sidx] = pack_h2(fre, fim);
  } else {
    const float prob = fre * fre + fim * fim;    // prob of final basis index 'inv'
    float vq[NQB];
#pragma unroll
    for (int q = 0; q < NQB; ++q) {
      float v = (inv & (1 << (5 - q))) ? -prob : prob;  // sign = 1-2*bit
#pragma unroll
      for (int off = 1; off < 64; off <<= 1) v += __shfl_xor(v, off, 64);
      vq[q] = v;
    }
    if (lane < 16) {
      const int q = lane & 7;
      float sel = vq[0];
      if (q == 1) sel = vq[1];
      if (q == 2) sel = vq[2];
      if (q == 3) sel = vq[3];
      if (q == 4) sel = vq[4];
      if (q == 5) sel = vq[5];
      if (q == 6) sel = 1.0f;                    // ones column -> den via MFMA
      if (q == 7) sel = 0.0f;
      float outv;
      if (lane < 8) {
        outv = sel;                              // hi part
      } else {
        const float hi = (float)(_Float16)sel;   // lo part = residual
        outv = (q < 6) ? (sel - hi) : 0.0f;
      }
      Vt[lane * NT + tok] = __builtin_bit_cast(unsigned short, (_Float16)outv);
    }
  }
}

// ---------------------------------------------------------------------------
// Kernel 2: fused swap-test attention, MFMA end-to-end.
//  - IPW=32: 2 query rowtiles per wave. K-fragments (bfr/bfi) hoisted over
//    rowtiles -> kbuf ds_read_b128 and global_load_lds traffic HALVED per
//    MFMA (round-3 analysis: ds pipe ~60% busy was the limiter, not barriers).
//  - qIm registers eliminated: Im-product rotation applied to K instead
//    (bfi = rot16(k) ^ 0x00008000, once per ct, shared by both rowtiles) to
//    stay under the 128-VGPR occupancy cliff.
//  - W-MFMA pipelined one chunk behind through double-buffered wbuf: the
//    exp->pack->ds_write->ds_read->MFMA round-trip leaves the critical path.
//  - single barrier per chunk; stage(c+1) in flight across chunk c's compute.
// MFMA 16x16x32 layouts:
//   A/B: row/col = lane&15, k = (lane>>4)*8 + j;  D: col = lane&15, row = (lane>>4)*4 + r
// ---------------------------------------------------------------------------
__global__ __launch_bounds__(256, 2) void attn_kernel(
    const uint4* __restrict__ Are, const uint4* __restrict__ Bk,
    const unsigned short* __restrict__ Vt, float* __restrict__ part)
{
  __shared__ uint4 kbuf[2][CHUNK * 16];                               // 16 KiB
  __shared__ __align__(16) unsigned short wbuf[2][WPB][2][16][WSTRIDE]; // 20 KiB

  const int tid  = threadIdx.x;
  const int lane = tid & 63;
  const int wave = tid >> 6;
  const int col  = lane & 15;
  const int quad = lane >> 4;

  const int ib = blockIdx.x & (NBI - 1);
  const int js = blockIdx.x >> 6;                 // / NBI (NBI == 64)
  const int ibase = ib * IPB + wave * IPW;
  const int jbase0 = js * JSLICE;

  // Query fragments (MFMA B operand), 2 rowtiles, kept resident (32 VGPR).
  f16x8 qRe[2][4];
#pragma unroll
  for (int rt = 0; rt < 2; ++rt) {
    const uint4* pr = Are + (ibase + rt * 16 + col) * 16 + quad;
#pragma unroll
    for (int s = 0; s < 4; ++s) qRe[rt][s] = __builtin_bit_cast(f16x8, pr[s * 4]);
  }

  // per-lane swizzled kbuf byte offsets: u' = (s*4+quad) ^ col  (key&15 == col)
  int koff[4];
#pragma unroll
  for (int s = 0; s < 4; ++s) koff[s] = (((s * 4 + quad) ^ col) << 4);

  f32x4 acc[2] = {{0.f, 0.f, 0.f, 0.f}, {0.f, 0.f, 0.f, 0.f}};

  // stage chunk c (8 KiB = 32 keys x 256B) into kbuf[buf]: 2 x 1KiB per wave
  auto stage = [&](int buf, int c) {
#pragma unroll
    for (int r = 0; r < 2; ++r) {
      const int slot = wave * 2 + r;              // 0..7, 64 uint4 each
      GLOAD_LDS16(Bk + (size_t)(jbase0 + c * CHUNK) * 16 + slot * 64 + lane,
                  &kbuf[buf][slot * 64]);
    }
  };

  // prologue: stage chunk 0, drain own loads, barrier -> all waves' chunk 0 in LDS
  stage(0, 0);
  asm volatile("s_waitcnt vmcnt(0)" ::: "memory");
  __builtin_amdgcn_s_barrier();
  asm volatile("" ::: "memory");

  f16x8 vb_prev;
#pragma unroll 1
  for (int c = 0; c < NCHUNK; ++c) {
    const int cur = c & 1;
    const int jb = jbase0 + c * CHUNK;
    // next chunk's stage at TOP: in flight across this chunk's compute
    if (c + 1 < NCHUNK) stage(cur ^ 1, c + 1);
    // V fragment for this 32-key group (consumed NEXT iteration)
    const f16x8 vb = *(const f16x8*)(Vt + (size_t)col * NT + jb + quad * 8);
    // previous chunk's W fragments (written last iter by this wave; ds in-order)
    f16x8 wA0, wA1;
    if (c > 0) {
      wA0 = *(const f16x8*)&wbuf[cur ^ 1][wave][0][col][quad * 8];
      wA1 = *(const f16x8*)&wbuf[cur ^ 1][wave][1][col][quad * 8];
    }

#pragma unroll
    for (int ct = 0; ct < 2; ++ct) {
      const char* kb = (const char*)kbuf[cur] + (ct * 16 + col) * 256;
      f16x8 bfr[4], bfi[4];
#pragma unroll
      for (int s = 0; s < 4; ++s) {
        const uint4 u = *(const uint4*)(kb + koff[s]);
        uint4 w;                                   // (kr,ki) -> (-ki, kr)
        w.x = ((u.x << 16) | (u.x >> 16)) ^ 0x00008000u;
        w.y = ((u.y << 16) | (u.y >> 16)) ^ 0x00008000u;
        w.z = ((u.z << 16) | (u.z >> 16)) ^ 0x00008000u;
        w.w = ((u.w << 16) | (u.w >> 16)) ^ 0x00008000u;
        bfr[s] = __builtin_bit_cast(f16x8, u);
        bfi[s] = __builtin_bit_cast(f16x8, w);
      }
#pragma unroll
      for (int rt = 0; rt < 2; ++rt) {
        f32x4 aR = {0.f, 0.f, 0.f, 0.f};
        f32x4 aI = {0.f, 0.f, 0.f, 0.f};
#pragma unroll
        for (int s = 0; s < 4; ++s) {
          aR = __builtin_amdgcn_mfma_f32_16x16x32_f16(bfr[s], qRe[rt][s], aR, 0, 0, 0);
          aI = __builtin_amdgcn_mfma_f32_16x16x32_f16(bfi[s], qRe[rt][s], aI, 0, 0, 0);
        }
        // lane holds keys ct*16+quad*4..+3 for query row 'col' of rowtile rt
        const float w0 = __expf(aR[0] * aR[0] + aI[0] * aI[0]);
        const float w1 = __expf(aR[1] * aR[1] + aI[1] * aI[1]);
        const float w2 = __expf(aR[2] * aR[2] + aI[2] * aI[2]);
        const float w3 = __expf(aR[3] * aR[3] + aI[3] * aI[3]);
        *(uint2*)&wbuf[cur][wave][rt][col][ct * 16 + quad * 4] =
            make_uint2(pkrtz(w0, w1), pkrtz(w2, w3));
      }
    }
    // pipelined W-MFMA for chunk c-1 (wave-local LDS, no barrier involved)
    if (c > 0) {
      acc[0] = __builtin_amdgcn_mfma_f32_16x16x32_f16(wA0, vb_prev, acc[0], 0, 0, 0);
      acc[1] = __builtin_amdgcn_mfma_f32_16x16x32_f16(wA1, vb_prev, acc[1], 0, 0, 0);
    }
    vb_prev = vb;

    if (c + 1 < NCHUNK) {
      asm volatile("s_waitcnt vmcnt(0)" ::: "memory");
      __builtin_amdgcn_s_barrier();
      asm volatile("" ::: "memory");
    }
  }
  // epilogue: W-MFMA for the last chunk
  {
    const int cur = (NCHUNK - 1) & 1;
    const f16x8 wA0 = *(const f16x8*)&wbuf[cur][wave][0][col][quad * 8];
    const f16x8 wA1 = *(const f16x8*)&wbuf[cur][wave][1][col][quad * 8];
    acc[0] = __builtin_amdgcn_mfma_f32_16x16x32_f16(wA0, vb_prev, acc[0], 0, 0, 0);
    acc[1] = __builtin_amdgcn_mfma_f32_16x16x32_f16(wA1, vb_prev, acc[1], 0, 0, 0);
  }

  // combine hi (cols 0..6) + lo (cols 8..14) and write partials
#pragma unroll
  for (int rt = 0; rt < 2; ++rt) {
    float res[4];
#pragma unroll
    for (int r = 0; r < 4; ++r) res[r] = acc[rt][r] + __shfl_xor(acc[rt][r], 8, 64);
    if (col < 8) {
      float* p = part + ((size_t)(js * NT + ibase + rt * 16 + quad * 4)) * 8 + col;
#pragma unroll
      for (int r = 0; r < 4; ++r) p[r * 8] = res[r];  // col6=den, col7=0
    }
  }
}

// ---------------------------------------------------------------------------
// Kernel 3: combine the 16 j-slice partials, normalize, emit float32.
// ---------------------------------------------------------------------------
__global__ __launch_bounds__(256) void combine_kernel(
    const float* __restrict__ part, float* __restrict__ out)
{
  const int row = blockIdx.x * 256 + threadIdx.x;
  float acc[7] = {0.f, 0.f, 0.f, 0.f, 0.f, 0.f, 0.f};
#pragma unroll
  for (int js = 0; js < JSPLIT; ++js) {
    const float* p = part + ((size_t)(js * NT + row)) * 8;
#pragma unroll
    for (int q = 0; q < 7; ++q) acc[q] += p[q];
  }
  const float inv = 1.0f / acc[6];
#pragma unroll
  for (int q = 0; q < 6; ++q)
    out[row * 6 + q] = acc[q] * inv;
}

// ---------------------------------------------------------------------------
// Workspace layout (bytes):
//   Are  @ 0        : 8192*64*4 = 2 MiB   (fp16 pairs packed in u32, linear)
//   Bk   @ 2 MiB    : 2 MiB               (fp16 pairs, uint4-XOR-preswizzled)
//   Vt   @ 4 MiB    : 16*8192*2 = 256 KiB (fp16 [V|1|Vlo] rows)
//   part @ 4.25 MiB : 16*8192*8*4 = 4 MiB
//   total 8.25 MiB
// ---------------------------------------------------------------------------
extern "C" void kernel_launch(void* const* d_in, const int* in_sizes, int n_in,
                              void* d_out, int out_size, void* d_ws, size_t ws_size,
                              hipStream_t stream) {
  const float* x  = (const float*)d_in[0];
  const float* pq = (const float*)d_in[1];
  const float* pk = (const float*)d_in[2];
  const float* pv = (const float*)d_in[3];
  char* ws = (char*)d_ws;
  unsigned int*   Are = (unsigned int*)(ws);
  unsigned int*   Bk  = (unsigned int*)(ws + (size_t)(2u << 20));
  unsigned short* Vt  = (unsigned short*)(ws + (size_t)(4u << 20));
  float*          prt = (float*)(ws + (size_t)(4u << 20) + (size_t)(256u << 10));

  prep_kernel<<<(NT * 3) / 4, 256, 0, stream>>>(x, pq, pk, pv, Are, Bk, Vt);
  attn_kernel<<<NBI * JSPLIT, 256, 0, stream>>>((const uint4*)Are, (const uint4*)Bk,
                                                Vt, prt);
  combine_kernel<<<NT / 256, 256, 0, stream>>>(prt, (float*)d_out);
}